// Round 1
// baseline (8687.482 us; speedup 1.0000x reference)
//
#include <hip/hip_runtime.h>

#define NN 50000
#define NE 800000
#define LEAKY 0.25f

// ---------------- GEMM: C[M,N] = A[M,K] @ B[K,N], all row-major f32 ----------------
template<int BM, int BN, int BK>
__global__ void gemm_f32(const float* __restrict__ A, const float* __restrict__ B,
                         float* __restrict__ C, int M, int N, int K) {
    __shared__ float As[BK][BM + 1];
    __shared__ float Bs[BK][BN + 1];
    const int tid = threadIdx.x;          // 256 threads
    const int tx = tid & 15;              // 0..15
    const int ty = tid >> 4;              // 0..15
    const int m0 = blockIdx.y * BM;
    const int n0 = blockIdx.x * BN;

    float acc[4][4] = {};

    for (int k0 = 0; k0 < K; k0 += BK) {
        // load A tile (BM x BK) -> As[k][m]
        #pragma unroll
        for (int l = tid; l < BM * BK; l += 256) {
            int r = l / BK, c = l % BK;
            int gr = m0 + r;
            float v = 0.f;
            if (gr < M) v = A[(size_t)gr * K + (k0 + c)];
            As[c][r] = v;
        }
        // load B tile (BK x BN) -> Bs[k][n]
        #pragma unroll
        for (int l = tid; l < BK * BN; l += 256) {
            int r = l / BN, c = l % BN;
            Bs[r][c] = B[(size_t)(k0 + r) * N + (n0 + c)];
        }
        __syncthreads();
        #pragma unroll
        for (int kk = 0; kk < BK; ++kk) {
            float a[4], b[4];
            #pragma unroll
            for (int i = 0; i < 4; ++i) a[i] = As[kk][ty * 4 + i];
            #pragma unroll
            for (int j = 0; j < 4; ++j) b[j] = Bs[kk][tx * 4 + j];
            #pragma unroll
            for (int i = 0; i < 4; ++i)
                #pragma unroll
                for (int j = 0; j < 4; ++j)
                    acc[i][j] += a[i] * b[j];
        }
        __syncthreads();
    }

    #pragma unroll
    for (int i = 0; i < 4; ++i) {
        int gr = m0 + ty * 4 + i;
        if (gr >= M) continue;
        #pragma unroll
        for (int j = 0; j < 4; ++j) {
            C[(size_t)gr * N + (n0 + tx * 4 + j)] = acc[i][j];
        }
    }
}

// ---------------- SpMM scatter: agg[row[e]] += vals[e] * support[col[e]] ----------------
template<int DIM>
__global__ void spmm_atomic(const float* __restrict__ support,
                            const int* __restrict__ row,
                            const int* __restrict__ col,
                            const float* __restrict__ vals,
                            float* __restrict__ agg) {
    const int F4 = DIM / 4;
    long long idx = (long long)blockIdx.x * blockDim.x + threadIdx.x;
    long long total = (long long)NE * F4;
    if (idx >= total) return;
    int e  = (int)(idx / F4);
    int f4 = (int)(idx % F4);
    float w = vals[e];
    int c = col[e];
    int r = row[e];
    float4 v = ((const float4*)support)[(size_t)c * F4 + f4];
    float* dst = agg + (size_t)r * DIM + f4 * 4;
    atomicAdd(dst + 0, v.x * w);
    atomicAdd(dst + 1, v.y * w);
    atomicAdd(dst + 2, v.z * w);
    atomicAdd(dst + 3, v.w * w);
}

// ---------------- bias + leaky relu (float4) ----------------
__global__ void bias_lrelu4(const float4* __restrict__ agg,
                            const float* __restrict__ bias,
                            float4* __restrict__ out,
                            int dim4, long long total4) {
    long long idx = (long long)blockIdx.x * blockDim.x + threadIdx.x;
    if (idx >= total4) return;
    int f4 = (int)(idx % dim4);
    float4 v = agg[idx];
    float4 bb = ((const float4*)bias)[f4];
    float4 r;
    r.x = v.x + bb.x; r.x = (r.x >= 0.f) ? r.x : LEAKY * r.x;
    r.y = v.y + bb.y; r.y = (r.y >= 0.f) ? r.y : LEAKY * r.y;
    r.z = v.z + bb.z; r.z = (r.z >= 0.f) ? r.z : LEAKY * r.z;
    r.w = v.w + bb.w; r.w = (r.w >= 0.f) ? r.w : LEAKY * r.w;
    out[idx] = r;
}

extern "C" void kernel_launch(void* const* d_in, const int* in_sizes, int n_in,
                              void* d_out, int out_size, void* d_ws, size_t ws_size,
                              hipStream_t stream) {
    const float* x    = (const float*)d_in[0];
    const int*   row  = (const int*)d_in[1];
    const int*   col  = (const int*)d_in[2];
    const float* vals = (const float*)d_in[3];
    const float* W1 = (const float*)d_in[4];  const float* b1 = (const float*)d_in[5];
    const float* W2 = (const float*)d_in[6];  const float* b2 = (const float*)d_in[7];
    const float* W3 = (const float*)d_in[8];  const float* b3 = (const float*)d_in[9];
    const float* W4 = (const float*)d_in[10]; const float* b4 = (const float*)d_in[11];

    // workspace layout: S | A | H  (each 50000*256 f32)
    float* S = (float*)d_ws;
    float* A = S + (size_t)NN * 256;
    float* H = A + (size_t)NN * 256;
    float* out = (float*)d_out;

    auto run_layer = [&](const float* in, int K, const float* W, const float* b,
                         int dim, float* hout) {
        dim3 grid(dim / 64, (NN + 63) / 64);
        gemm_f32<64, 64, 16><<<grid, 256, 0, stream>>>(in, W, S, NN, dim, K);
        hipMemsetAsync(A, 0, (size_t)NN * dim * sizeof(float), stream);
        long long total = (long long)NE * (dim / 4);
        int blocks = (int)((total + 255) / 256);
        if (dim == 256)
            spmm_atomic<256><<<blocks, 256, 0, stream>>>(S, row, col, vals, A);
        else
            spmm_atomic<128><<<blocks, 256, 0, stream>>>(S, row, col, vals, A);
        long long total4 = (long long)NN * dim / 4;
        bias_lrelu4<<<(int)((total4 + 255) / 256), 256, 0, stream>>>(
            (const float4*)A, b, (float4*)hout, dim / 4, total4);
    };

    run_layer(x, 512, W1, b1, 256, H);
    run_layer(H, 256, W2, b2, 256, H);
    run_layer(H, 256, W3, b3, 128, H);
    run_layer(H, 128, W4, b4, 128, out);
}

// Round 2
// 1149.205 us; speedup vs baseline: 7.5596x; 7.5596x over previous
//
#include <hip/hip_runtime.h>

#define NN 50000
#define NE 800000
#define LEAKY 0.25f

// ---------------- GEMM: C[M,N] = A[M,K] @ B[K,N], all row-major f32 ----------------
template<int BM, int BN, int BK>
__global__ void gemm_f32(const float* __restrict__ A, const float* __restrict__ B,
                         float* __restrict__ C, int M, int N, int K) {
    __shared__ float As[BK][BM + 1];
    __shared__ float Bs[BK][BN + 1];
    const int tid = threadIdx.x;          // 256 threads
    const int tx = tid & 15;              // 0..15
    const int ty = tid >> 4;              // 0..15
    const int m0 = blockIdx.y * BM;
    const int n0 = blockIdx.x * BN;

    float acc[4][4] = {};

    for (int k0 = 0; k0 < K; k0 += BK) {
        #pragma unroll
        for (int l = tid; l < BM * BK; l += 256) {
            int r = l / BK, c = l % BK;
            int gr = m0 + r;
            float v = 0.f;
            if (gr < M) v = A[(size_t)gr * K + (k0 + c)];
            As[c][r] = v;
        }
        #pragma unroll
        for (int l = tid; l < BK * BN; l += 256) {
            int r = l / BN, c = l % BN;
            Bs[r][c] = B[(size_t)(k0 + r) * N + (n0 + c)];
        }
        __syncthreads();
        #pragma unroll
        for (int kk = 0; kk < BK; ++kk) {
            float a[4], b[4];
            #pragma unroll
            for (int i = 0; i < 4; ++i) a[i] = As[kk][ty * 4 + i];
            #pragma unroll
            for (int j = 0; j < 4; ++j) b[j] = Bs[kk][tx * 4 + j];
            #pragma unroll
            for (int i = 0; i < 4; ++i)
                #pragma unroll
                for (int j = 0; j < 4; ++j)
                    acc[i][j] += a[i] * b[j];
        }
        __syncthreads();
    }

    #pragma unroll
    for (int i = 0; i < 4; ++i) {
        int gr = m0 + ty * 4 + i;
        if (gr >= M) continue;
        #pragma unroll
        for (int j = 0; j < 4; ++j) {
            C[(size_t)gr * N + (n0 + tx * 4 + j)] = acc[i][j];
        }
    }
}

// ---------------- CSR construction ----------------
__global__ void hist_rows(const int* __restrict__ row, int* __restrict__ cnt) {
    int e = blockIdx.x * blockDim.x + threadIdx.x;
    if (e < NE) atomicAdd(&cnt[row[e]], 1);
}

// single-block exclusive scan over cnt[NN] -> rowptr[NN+1], rowcur copy
__global__ void scan_rowptr(const int* __restrict__ cnt,
                            int* __restrict__ rowptr, int* __restrict__ rowcur) {
    __shared__ int sums[1024];
    const int T = 1024;
    const int CH = (NN + T - 1) / T;   // 49
    int t = threadIdx.x;
    int begin = t * CH;
    int end = begin + CH; if (end > NN) end = NN;
    int s = 0;
    for (int i = begin; i < end && i < NN; ++i) s += cnt[i];
    sums[t] = s;
    __syncthreads();
    for (int off = 1; off < T; off <<= 1) {
        int v = (t >= off) ? sums[t - off] : 0;
        __syncthreads();
        sums[t] += v;
        __syncthreads();
    }
    int prefix = (t == 0) ? 0 : sums[t - 1];
    for (int i = begin; i < end && i < NN; ++i) {
        rowptr[i] = prefix; rowcur[i] = prefix;
        prefix += cnt[i];
    }
    if (t == T - 1) rowptr[NN] = sums[T - 1];
}

__global__ void scatter_edges(const int* __restrict__ row, const int* __restrict__ col,
                              const float* __restrict__ vals,
                              int* __restrict__ rowcur,
                              int* __restrict__ ecol, float* __restrict__ ew) {
    int e = blockIdx.x * blockDim.x + threadIdx.x;
    if (e < NE) {
        int p = atomicAdd(&rowcur[row[e]], 1);
        ecol[p] = col[e];
        ew[p]   = vals[e];
    }
}

// ---------------- SpMM gather + bias + leakyReLU fused ----------------
// DIM/4 lanes per row, float4 per lane; accumulate in registers, single write.
template<int DIM>
__global__ void spmm_gather(const float* __restrict__ support,
                            const int* __restrict__ rowptr,
                            const int* __restrict__ ecol,
                            const float* __restrict__ ew,
                            const float* __restrict__ bias,
                            float* __restrict__ out) {
    constexpr int LPR = DIM / 4;        // lanes per row (64 or 32)
    constexpr int RPB = 256 / LPR;      // rows per 256-thread block
    int r = blockIdx.x * RPB + threadIdx.x / LPR;
    int lane = threadIdx.x % LPR;
    if (r >= NN) return;
    int s = rowptr[r], e = rowptr[r + 1];
    float4 acc = {0.f, 0.f, 0.f, 0.f};
    for (int i = s; i < e; ++i) {
        int c = ecol[i];
        float w = ew[i];
        float4 v = ((const float4*)support)[(size_t)c * LPR + lane];
        acc.x += w * v.x; acc.y += w * v.y; acc.z += w * v.z; acc.w += w * v.w;
    }
    float4 bb = ((const float4*)bias)[lane];
    acc.x += bb.x; acc.y += bb.y; acc.z += bb.z; acc.w += bb.w;
    acc.x = (acc.x >= 0.f) ? acc.x : LEAKY * acc.x;
    acc.y = (acc.y >= 0.f) ? acc.y : LEAKY * acc.y;
    acc.z = (acc.z >= 0.f) ? acc.z : LEAKY * acc.z;
    acc.w = (acc.w >= 0.f) ? acc.w : LEAKY * acc.w;
    ((float4*)out)[(size_t)r * LPR + lane] = acc;
}

extern "C" void kernel_launch(void* const* d_in, const int* in_sizes, int n_in,
                              void* d_out, int out_size, void* d_ws, size_t ws_size,
                              hipStream_t stream) {
    const float* x    = (const float*)d_in[0];
    const int*   row  = (const int*)d_in[1];
    const int*   col  = (const int*)d_in[2];
    const float* vals = (const float*)d_in[3];
    const float* W1 = (const float*)d_in[4];  const float* b1 = (const float*)d_in[5];
    const float* W2 = (const float*)d_in[6];  const float* b2 = (const float*)d_in[7];
    const float* W3 = (const float*)d_in[8];  const float* b3 = (const float*)d_in[9];
    const float* W4 = (const float*)d_in[10]; const float* b4 = (const float*)d_in[11];

    // workspace layout: S | H | cnt | rowptr | rowcur | ecol | ew
    float* S = (float*)d_ws;
    float* H = S + (size_t)NN * 256;
    int* cnt    = (int*)(H + (size_t)NN * 256);
    int* rowptr = cnt + NN;
    int* rowcur = rowptr + (NN + 1);
    int* ecol   = rowcur + (NN + 1);
    float* ew   = (float*)(ecol + NE);
    float* out  = (float*)d_out;

    // ---- build CSR (once; reused by all 4 layers) ----
    hipMemsetAsync(cnt, 0, NN * sizeof(int), stream);
    hist_rows<<<(NE + 255) / 256, 256, 0, stream>>>(row, cnt);
    scan_rowptr<<<1, 1024, 0, stream>>>(cnt, rowptr, rowcur);
    scatter_edges<<<(NE + 255) / 256, 256, 0, stream>>>(row, col, vals, rowcur, ecol, ew);

    auto run_layer = [&](const float* in, int K, const float* W, const float* b,
                         int dim, float* hout) {
        dim3 grid(dim / 64, (NN + 63) / 64);
        gemm_f32<64, 64, 16><<<grid, 256, 0, stream>>>(in, W, S, NN, dim, K);
        if (dim == 256) {
            spmm_gather<256><<<(NN + 3) / 4, 256, 0, stream>>>(S, rowptr, ecol, ew, b, hout);
        } else {
            spmm_gather<128><<<(NN + 7) / 8, 256, 0, stream>>>(S, rowptr, ecol, ew, b, hout);
        }
    };

    run_layer(x, 512, W1, b1, 256, H);
    run_layer(H, 256, W2, b2, 256, H);
    run_layer(H, 256, W3, b3, 128, H);
    run_layer(H, 128, W4, b4, 128, out);
}

// Round 3
// 664.944 us; speedup vs baseline: 13.0650x; 1.7283x over previous
//
#include <hip/hip_runtime.h>
#include <hip/hip_bf16.h>

#define NN 50000
#define NE 800000
#define LEAKY 0.25f

typedef __attribute__((ext_vector_type(8))) short bf16x8;
typedef __attribute__((ext_vector_type(4))) float f32x4;

static __device__ __forceinline__ ushort f2bf(float f) {
    union { __hip_bfloat16 h; ushort u; } cv;
    cv.h = __float2bfloat16(f);
    return cv.u;
}

// ---------------- casts ----------------
__global__ void cast_bf16_vec(const float4* __restrict__ in, ushort4* __restrict__ out, int n4) {
    int i = blockIdx.x * blockDim.x + threadIdx.x;
    if (i >= n4) return;
    float4 v = in[i];
    ushort4 o;
    o.x = f2bf(v.x); o.y = f2bf(v.y); o.z = f2bf(v.z); o.w = f2bf(v.w);
    out[i] = o;
}

__global__ void cast_transpose_w(const float* __restrict__ W, ushort* __restrict__ Wt, int K, int N) {
    int idx = blockIdx.x * blockDim.x + threadIdx.x;
    if (idx >= K * N) return;
    int k = idx / N, n = idx % N;
    Wt[n * K + k] = f2bf(W[idx]);
}

// ---------------- bf16 MFMA GEMM: C[M,N] = A[M,K] @ Bt[N,K]^T ----------------
// 128x128 tile, BK=32, 4 waves each computing 64x64 via 4x4 frags of 16x16x32.
__global__ __launch_bounds__(256) void gemm_bf16(
    const ushort* __restrict__ A, const ushort* __restrict__ Bt,
    float* __restrict__ C, int M, int N, int K)
{
    __shared__ ushort As[128 * 32];
    __shared__ ushort Bs[128 * 32];
    const int tid  = threadIdx.x;
    const int lane = tid & 63;
    const int wid  = tid >> 6;
    const int wr = wid >> 1, wc = wid & 1;
    const int m0 = blockIdx.x * 128;
    const int n0 = blockIdx.y * 128;

    // staging: thread t loads 16B (8 bf16) from row (t>>2) [+64], col-chunk (t&3)*8
    int ar1 = m0 + (tid >> 2);      if (ar1 >= M) ar1 = M - 1;
    int ar2 = m0 + 64 + (tid >> 2); if (ar2 >= M) ar2 = M - 1;
    const int br1 = n0 + (tid >> 2);
    const int br2 = br1 + 64;
    const int ccol = (tid & 3) * 8;

    const ushort* gA1 = A + (size_t)ar1 * K + ccol;
    const ushort* gA2 = A + (size_t)ar2 * K + ccol;
    const ushort* gB1 = Bt + (size_t)br1 * K + ccol;
    const ushort* gB2 = Bt + (size_t)br2 * K + ccol;

    // wave-uniform LDS bases; HW adds lane*16
    char* ldsA = (char*)As + wid * 1024;
    char* ldsB = (char*)Bs + wid * 1024;

    const int fr = lane & 15;   // row (A) / col (B) within 16
    const int fq = lane >> 4;   // k-chunk 0..3

    const ushort* fragA = As + (wr * 64 + fr) * 32 + fq * 8;
    const ushort* fragB = Bs + (wc * 64 + fr) * 32 + fq * 8;

    f32x4 acc[4][4];
    #pragma unroll
    for (int i = 0; i < 4; ++i)
        #pragma unroll
        for (int j = 0; j < 4; ++j)
            acc[i][j] = {0.f, 0.f, 0.f, 0.f};

    for (int k0 = 0; k0 < K; k0 += 32) {
        __builtin_amdgcn_global_load_lds((const __attribute__((address_space(1))) void*)(gA1 + k0),
                                         (__attribute__((address_space(3))) void*)(ldsA), 16, 0, 0);
        __builtin_amdgcn_global_load_lds((const __attribute__((address_space(1))) void*)(gA2 + k0),
                                         (__attribute__((address_space(3))) void*)(ldsA + 4096), 16, 0, 0);
        __builtin_amdgcn_global_load_lds((const __attribute__((address_space(1))) void*)(gB1 + k0),
                                         (__attribute__((address_space(3))) void*)(ldsB), 16, 0, 0);
        __builtin_amdgcn_global_load_lds((const __attribute__((address_space(1))) void*)(gB2 + k0),
                                         (__attribute__((address_space(3))) void*)(ldsB + 4096), 16, 0, 0);
        __syncthreads();   // drains vmcnt: staging complete

        bf16x8 a[4], b[4];
        #pragma unroll
        for (int mi = 0; mi < 4; ++mi) a[mi] = *(const bf16x8*)(fragA + mi * 16 * 32);
        #pragma unroll
        for (int ni = 0; ni < 4; ++ni) b[ni] = *(const bf16x8*)(fragB + ni * 16 * 32);
        #pragma unroll
        for (int mi = 0; mi < 4; ++mi)
            #pragma unroll
            for (int ni = 0; ni < 4; ++ni)
                acc[mi][ni] = __builtin_amdgcn_mfma_f32_16x16x32_bf16(a[mi], b[ni], acc[mi][ni], 0, 0, 0);
        __syncthreads();   // frag reads done before next stage overwrites
    }

    // epilogue: C/D layout col=lane&15, row=(lane>>4)*4+reg
    #pragma unroll
    for (int mi = 0; mi < 4; ++mi) {
        #pragma unroll
        for (int j = 0; j < 4; ++j) {
            int row = m0 + wr * 64 + mi * 16 + fq * 4 + j;
            if (row >= M) continue;
            #pragma unroll
            for (int ni = 0; ni < 4; ++ni) {
                int colg = n0 + wc * 64 + ni * 16 + fr;
                C[(size_t)row * N + colg] = acc[mi][ni][j];
            }
        }
    }
}

// ---------------- CSR construction ----------------
__global__ void hist_rows(const int* __restrict__ row, int* __restrict__ cnt) {
    int e = blockIdx.x * blockDim.x + threadIdx.x;
    if (e < NE) atomicAdd(&cnt[row[e]], 1);
}

__global__ void scan_rowptr(const int* __restrict__ cnt,
                            int* __restrict__ rowptr, int* __restrict__ rowcur) {
    __shared__ int sums[1024];
    const int T = 1024;
    const int CH = (NN + T - 1) / T;
    int t = threadIdx.x;
    int begin = t * CH;
    int end = begin + CH; if (end > NN) end = NN;
    int s = 0;
    for (int i = begin; i < end; ++i) s += cnt[i];
    sums[t] = s;
    __syncthreads();
    for (int off = 1; off < T; off <<= 1) {
        int v = (t >= off) ? sums[t - off] : 0;
        __syncthreads();
        sums[t] += v;
        __syncthreads();
    }
    int prefix = (t == 0) ? 0 : sums[t - 1];
    for (int i = begin; i < end; ++i) {
        rowptr[i] = prefix; rowcur[i] = prefix;
        prefix += cnt[i];
    }
    if (t == T - 1) rowptr[NN] = sums[T - 1];
}

__global__ void scatter_edges(const int* __restrict__ row, const int* __restrict__ col,
                              const float* __restrict__ vals,
                              int* __restrict__ rowcur,
                              int* __restrict__ ecol, float* __restrict__ ew) {
    int e = blockIdx.x * blockDim.x + threadIdx.x;
    if (e < NE) {
        int p = atomicAdd(&rowcur[row[e]], 1);
        ecol[p] = col[e];
        ew[p]   = vals[e];
    }
}

// ---------------- SpMM gather + bias + leakyReLU fused ----------------
template<int DIM, bool OUT_BF16>
__global__ void spmm_gather(const float* __restrict__ support,
                            const int* __restrict__ rowptr,
                            const int* __restrict__ ecol,
                            const float* __restrict__ ew,
                            const float* __restrict__ bias,
                            void* __restrict__ out) {
    constexpr int LPR = DIM / 4;        // lanes per row
    constexpr int RPB = 256 / LPR;      // rows per block
    int r = blockIdx.x * RPB + threadIdx.x / LPR;
    int lane = threadIdx.x % LPR;
    if (r >= NN) return;
    int s = rowptr[r], e = rowptr[r + 1];
    float4 acc = {0.f, 0.f, 0.f, 0.f};
    for (int i = s; i < e; ++i) {
        int c = ecol[i];
        float w = ew[i];
        float4 v = ((const float4*)support)[(size_t)c * LPR + lane];
        acc.x += w * v.x; acc.y += w * v.y; acc.z += w * v.z; acc.w += w * v.w;
    }
    float4 bb = ((const float4*)bias)[lane];
    acc.x += bb.x; acc.y += bb.y; acc.z += bb.z; acc.w += bb.w;
    acc.x = (acc.x >= 0.f) ? acc.x : LEAKY * acc.x;
    acc.y = (acc.y >= 0.f) ? acc.y : LEAKY * acc.y;
    acc.z = (acc.z >= 0.f) ? acc.z : LEAKY * acc.z;
    acc.w = (acc.w >= 0.f) ? acc.w : LEAKY * acc.w;
    if (OUT_BF16) {
        ushort4 o;
        o.x = f2bf(acc.x); o.y = f2bf(acc.y); o.z = f2bf(acc.z); o.w = f2bf(acc.w);
        ((ushort4*)out)[(size_t)r * LPR + lane] = o;
    } else {
        ((float4*)out)[(size_t)r * LPR + lane] = acc;
    }
}

extern "C" void kernel_launch(void* const* d_in, const int* in_sizes, int n_in,
                              void* d_out, int out_size, void* d_ws, size_t ws_size,
                              hipStream_t stream) {
    const float* x    = (const float*)d_in[0];
    const int*   row  = (const int*)d_in[1];
    const int*   col  = (const int*)d_in[2];
    const float* vals = (const float*)d_in[3];
    const float* W1 = (const float*)d_in[4];  const float* b1 = (const float*)d_in[5];
    const float* W2 = (const float*)d_in[6];  const float* b2 = (const float*)d_in[7];
    const float* W3 = (const float*)d_in[8];  const float* b3 = (const float*)d_in[9];
    const float* W4 = (const float*)d_in[10]; const float* b4 = (const float*)d_in[11];

    // workspace: Xb (25.6M ushort, Hb aliases its start) | S (12.8M f32) | Wt (245760 ushort) | CSR
    ushort* Xb = (ushort*)d_ws;
    ushort* Hb = Xb;                            // alias: Xb dead after layer-1 GEMM
    float*  S  = (float*)(Xb + (size_t)NN * 512);
    ushort* Wt = (ushort*)(S + (size_t)NN * 256);
    ushort* Wt1 = Wt;
    ushort* Wt2 = Wt1 + 512 * 256;
    ushort* Wt3 = Wt2 + 256 * 256;
    ushort* Wt4 = Wt3 + 256 * 128;
    int* cnt    = (int*)(Wt4 + 128 * 128);
    int* rowptr = cnt + NN;
    int* rowcur = rowptr + (NN + 1);
    int* ecol   = rowcur + (NN + 1);
    float* ew   = (float*)(ecol + NE);
    float* out  = (float*)d_out;

    // ---- casts ----
    {
        int n4 = NN * 512 / 4;
        cast_bf16_vec<<<(n4 + 255) / 256, 256, 0, stream>>>((const float4*)x, (ushort4*)Xb, n4);
        cast_transpose_w<<<(512 * 256 + 255) / 256, 256, 0, stream>>>(W1, Wt1, 512, 256);
        cast_transpose_w<<<(256 * 256 + 255) / 256, 256, 0, stream>>>(W2, Wt2, 256, 256);
        cast_transpose_w<<<(256 * 128 + 255) / 256, 256, 0, stream>>>(W3, Wt3, 256, 128);
        cast_transpose_w<<<(128 * 128 + 255) / 256, 256, 0, stream>>>(W4, Wt4, 128, 128);
    }

    // ---- build CSR ----
    hipMemsetAsync(cnt, 0, NN * sizeof(int), stream);
    hist_rows<<<(NE + 255) / 256, 256, 0, stream>>>(row, cnt);
    scan_rowptr<<<1, 1024, 0, stream>>>(cnt, rowptr, rowcur);
    scatter_edges<<<(NE + 255) / 256, 256, 0, stream>>>(row, col, vals, rowcur, ecol, ew);

    const int MT = (NN + 127) / 128;  // 391

    // layer 1: [50000,512] @ [512,256]
    gemm_bf16<<<dim3(MT, 2), 256, 0, stream>>>(Xb, Wt1, S, NN, 256, 512);
    spmm_gather<256, true><<<(NN + 3) / 4, 256, 0, stream>>>(S, rowptr, ecol, ew, b1, Hb);
    // layer 2: [50000,256] @ [256,256]
    gemm_bf16<<<dim3(MT, 2), 256, 0, stream>>>(Hb, Wt2, S, NN, 256, 256);
    spmm_gather<256, true><<<(NN + 3) / 4, 256, 0, stream>>>(S, rowptr, ecol, ew, b2, Hb);
    // layer 3: [50000,256] @ [256,128]
    gemm_bf16<<<dim3(MT, 1), 256, 0, stream>>>(Hb, Wt3, S, NN, 128, 256);
    spmm_gather<128, true><<<(NN + 7) / 8, 256, 0, stream>>>(S, rowptr, ecol, ew, b3, Hb);
    // layer 4: [50000,128] @ [128,128]
    gemm_bf16<<<dim3(MT, 1), 256, 0, stream>>>(Hb, Wt4, S, NN, 128, 128);
    spmm_gather<128, false><<<(NN + 7) / 8, 256, 0, stream>>>(S, rowptr, ecol, ew, b4, out);
}

// Round 4
// 527.282 us; speedup vs baseline: 16.4760x; 1.2611x over previous
//
#include <hip/hip_runtime.h>
#include <hip/hip_bf16.h>

#define NN 50000
#define NE 800000
#define LEAKY 0.25f

typedef __attribute__((ext_vector_type(8))) short bf16x8;
typedef __attribute__((ext_vector_type(8))) ushort u16x8;
typedef __attribute__((ext_vector_type(4))) float f32x4;

static __device__ __forceinline__ ushort f2bf(float f) {
    union { __hip_bfloat16 h; ushort u; } cv;
    cv.h = __float2bfloat16(f);
    return cv.u;
}
static __device__ __forceinline__ float bf2f(ushort u) {
    union { unsigned u; float f; } cv;
    cv.u = ((unsigned)u) << 16;
    return cv.f;
}

// ---------------- casts ----------------
__global__ void cast_bf16_vec(const float4* __restrict__ in, ushort4* __restrict__ out, int n4) {
    int i = blockIdx.x * blockDim.x + threadIdx.x;
    if (i >= n4) return;
    float4 v = in[i];
    ushort4 o;
    o.x = f2bf(v.x); o.y = f2bf(v.y); o.z = f2bf(v.z); o.w = f2bf(v.w);
    out[i] = o;
}

__global__ void cast_transpose_w(const float* __restrict__ W, ushort* __restrict__ Wt, int K, int N) {
    int idx = blockIdx.x * blockDim.x + threadIdx.x;
    if (idx >= K * N) return;
    int k = idx / N, n = idx % N;
    Wt[n * K + k] = f2bf(W[idx]);
}

// ---------------- bf16 MFMA GEMM: C[M,N] = A[M,K] @ Bt[N,K]^T, C in bf16 ----------------
__global__ __launch_bounds__(256) void gemm_bf16(
    const ushort* __restrict__ A, const ushort* __restrict__ Bt,
    ushort* __restrict__ C, int M, int N, int K)
{
    __shared__ ushort As[128 * 32];
    __shared__ ushort Bs[128 * 32];
    const int tid  = threadIdx.x;
    const int lane = tid & 63;
    const int wid  = tid >> 6;
    const int wr = wid >> 1, wc = wid & 1;
    const int m0 = blockIdx.x * 128;
    const int n0 = blockIdx.y * 128;

    int ar1 = m0 + (tid >> 2);      if (ar1 >= M) ar1 = M - 1;
    int ar2 = m0 + 64 + (tid >> 2); if (ar2 >= M) ar2 = M - 1;
    const int br1 = n0 + (tid >> 2);
    const int br2 = br1 + 64;
    const int ccol = (tid & 3) * 8;

    const ushort* gA1 = A + (size_t)ar1 * K + ccol;
    const ushort* gA2 = A + (size_t)ar2 * K + ccol;
    const ushort* gB1 = Bt + (size_t)br1 * K + ccol;
    const ushort* gB2 = Bt + (size_t)br2 * K + ccol;

    char* ldsA = (char*)As + wid * 1024;
    char* ldsB = (char*)Bs + wid * 1024;

    const int fr = lane & 15;
    const int fq = lane >> 4;

    const ushort* fragA = As + (wr * 64 + fr) * 32 + fq * 8;
    const ushort* fragB = Bs + (wc * 64 + fr) * 32 + fq * 8;

    f32x4 acc[4][4];
    #pragma unroll
    for (int i = 0; i < 4; ++i)
        #pragma unroll
        for (int j = 0; j < 4; ++j)
            acc[i][j] = {0.f, 0.f, 0.f, 0.f};

    for (int k0 = 0; k0 < K; k0 += 32) {
        __builtin_amdgcn_global_load_lds((const __attribute__((address_space(1))) void*)(gA1 + k0),
                                         (__attribute__((address_space(3))) void*)(ldsA), 16, 0, 0);
        __builtin_amdgcn_global_load_lds((const __attribute__((address_space(1))) void*)(gA2 + k0),
                                         (__attribute__((address_space(3))) void*)(ldsA + 4096), 16, 0, 0);
        __builtin_amdgcn_global_load_lds((const __attribute__((address_space(1))) void*)(gB1 + k0),
                                         (__attribute__((address_space(3))) void*)(ldsB), 16, 0, 0);
        __builtin_amdgcn_global_load_lds((const __attribute__((address_space(1))) void*)(gB2 + k0),
                                         (__attribute__((address_space(3))) void*)(ldsB + 4096), 16, 0, 0);
        __syncthreads();

        bf16x8 a[4], b[4];
        #pragma unroll
        for (int mi = 0; mi < 4; ++mi) a[mi] = *(const bf16x8*)(fragA + mi * 16 * 32);
        #pragma unroll
        for (int ni = 0; ni < 4; ++ni) b[ni] = *(const bf16x8*)(fragB + ni * 16 * 32);
        #pragma unroll
        for (int mi = 0; mi < 4; ++mi)
            #pragma unroll
            for (int ni = 0; ni < 4; ++ni)
                acc[mi][ni] = __builtin_amdgcn_mfma_f32_16x16x32_bf16(a[mi], b[ni], acc[mi][ni], 0, 0, 0);
        __syncthreads();
    }

    #pragma unroll
    for (int mi = 0; mi < 4; ++mi) {
        #pragma unroll
        for (int j = 0; j < 4; ++j) {
            int row = m0 + wr * 64 + mi * 16 + fq * 4 + j;
            if (row >= M) continue;
            #pragma unroll
            for (int ni = 0; ni < 4; ++ni) {
                int colg = n0 + wc * 64 + ni * 16 + fr;
                C[(size_t)row * N + colg] = f2bf(acc[mi][ni][j]);
            }
        }
    }
}

// ---------------- CSR construction ----------------
__global__ void hist_rows(const int* __restrict__ row, int* __restrict__ cnt) {
    int e = blockIdx.x * blockDim.x + threadIdx.x;
    if (e < NE) atomicAdd(&cnt[row[e]], 1);
}

__global__ void scan_rowptr(const int* __restrict__ cnt,
                            int* __restrict__ rowptr, int* __restrict__ rowcur) {
    __shared__ int sums[1024];
    const int T = 1024;
    const int CH = (NN + T - 1) / T;
    int t = threadIdx.x;
    int begin = t * CH;
    int end = begin + CH; if (end > NN) end = NN;
    int s = 0;
    for (int i = begin; i < end; ++i) s += cnt[i];
    sums[t] = s;
    __syncthreads();
    for (int off = 1; off < T; off <<= 1) {
        int v = (t >= off) ? sums[t - off] : 0;
        __syncthreads();
        sums[t] += v;
        __syncthreads();
    }
    int prefix = (t == 0) ? 0 : sums[t - 1];
    for (int i = begin; i < end; ++i) {
        rowptr[i] = prefix; rowcur[i] = prefix;
        prefix += cnt[i];
    }
    if (t == T - 1) rowptr[NN] = sums[T - 1];
}

__global__ void scatter_edges(const int* __restrict__ row, const int* __restrict__ col,
                              const float* __restrict__ vals,
                              int* __restrict__ rowcur,
                              int* __restrict__ ecol, float* __restrict__ ew) {
    int e = blockIdx.x * blockDim.x + threadIdx.x;
    if (e < NE) {
        int p = atomicAdd(&rowcur[row[e]], 1);
        ecol[p] = col[e];
        ew[p]   = vals[e];
    }
}

// ---------------- SpMM gather (bf16 support) + bias + leakyReLU fused ----------------
// Each lane owns 8 contiguous features (16B bf16 load per edge), f32 accumulate.
template<int DIM, bool OUT_BF16>
__global__ void spmm_gather_bf16(const ushort* __restrict__ support,
                                 const int* __restrict__ rowptr,
                                 const int* __restrict__ ecol,
                                 const float* __restrict__ ew,
                                 const float* __restrict__ bias,
                                 void* __restrict__ out) {
    constexpr int LPR = DIM / 8;        // lanes per row (32 or 16)
    constexpr int RPB = 256 / LPR;      // rows per block (8 or 16)
    int r = blockIdx.x * RPB + threadIdx.x / LPR;
    int lane = threadIdx.x % LPR;
    if (r >= NN) return;
    int s = rowptr[r], e = rowptr[r + 1];
    float acc[8] = {};
    for (int i = s; i < e; ++i) {
        int c = ecol[i];
        float w = ew[i];
        u16x8 v = *(const u16x8*)(support + (size_t)c * DIM + lane * 8);
        #pragma unroll
        for (int j = 0; j < 8; ++j) acc[j] += w * bf2f(v[j]);
    }
    const float4 bb0 = ((const float4*)bias)[lane * 2];
    const float4 bb1 = ((const float4*)bias)[lane * 2 + 1];
    acc[0] += bb0.x; acc[1] += bb0.y; acc[2] += bb0.z; acc[3] += bb0.w;
    acc[4] += bb1.x; acc[5] += bb1.y; acc[6] += bb1.z; acc[7] += bb1.w;
    #pragma unroll
    for (int j = 0; j < 8; ++j) acc[j] = (acc[j] >= 0.f) ? acc[j] : LEAKY * acc[j];
    if (OUT_BF16) {
        ushort4 o0, o1;
        o0.x = f2bf(acc[0]); o0.y = f2bf(acc[1]); o0.z = f2bf(acc[2]); o0.w = f2bf(acc[3]);
        o1.x = f2bf(acc[4]); o1.y = f2bf(acc[5]); o1.z = f2bf(acc[6]); o1.w = f2bf(acc[7]);
        ((ushort4*)out)[(size_t)r * LPR * 2 + lane * 2]     = o0;
        ((ushort4*)out)[(size_t)r * LPR * 2 + lane * 2 + 1] = o1;
    } else {
        float4 f0 = {acc[0], acc[1], acc[2], acc[3]};
        float4 f1 = {acc[4], acc[5], acc[6], acc[7]};
        ((float4*)out)[(size_t)r * LPR * 2 + lane * 2]     = f0;
        ((float4*)out)[(size_t)r * LPR * 2 + lane * 2 + 1] = f1;
    }
}

extern "C" void kernel_launch(void* const* d_in, const int* in_sizes, int n_in,
                              void* d_out, int out_size, void* d_ws, size_t ws_size,
                              hipStream_t stream) {
    const float* x    = (const float*)d_in[0];
    const int*   row  = (const int*)d_in[1];
    const int*   col  = (const int*)d_in[2];
    const float* vals = (const float*)d_in[3];
    const float* W1 = (const float*)d_in[4];  const float* b1 = (const float*)d_in[5];
    const float* W2 = (const float*)d_in[6];  const float* b2 = (const float*)d_in[7];
    const float* W3 = (const float*)d_in[8];  const float* b3 = (const float*)d_in[9];
    const float* W4 = (const float*)d_in[10]; const float* b4 = (const float*)d_in[11];

    // workspace: Xb (NN*512 u16; Hb aliases) | S (NN*256 u16) | Wt | CSR
    ushort* Xb = (ushort*)d_ws;
    ushort* Hb = Xb;                        // Xb dead after layer-1 GEMM
    ushort* S  = Xb + (size_t)NN * 512;
    ushort* Wt1 = S + (size_t)NN * 256;
    ushort* Wt2 = Wt1 + 512 * 256;
    ushort* Wt3 = Wt2 + 256 * 256;
    ushort* Wt4 = Wt3 + 256 * 128;
    int* cnt    = (int*)(Wt4 + 128 * 128);
    int* rowptr = cnt + NN;
    int* rowcur = rowptr + (NN + 1);
    int* ecol   = rowcur + (NN + 1);
    float* ew   = (float*)(ecol + NE);
    float* out  = (float*)d_out;

    // ---- casts ----
    {
        int n4 = NN * 512 / 4;
        cast_bf16_vec<<<(n4 + 255) / 256, 256, 0, stream>>>((const float4*)x, (ushort4*)Xb, n4);
        cast_transpose_w<<<(512 * 256 + 255) / 256, 256, 0, stream>>>(W1, Wt1, 512, 256);
        cast_transpose_w<<<(256 * 256 + 255) / 256, 256, 0, stream>>>(W2, Wt2, 256, 256);
        cast_transpose_w<<<(256 * 128 + 255) / 256, 256, 0, stream>>>(W3, Wt3, 256, 128);
        cast_transpose_w<<<(128 * 128 + 255) / 256, 256, 0, stream>>>(W4, Wt4, 128, 128);
    }

    // ---- build CSR ----
    hipMemsetAsync(cnt, 0, NN * sizeof(int), stream);
    hist_rows<<<(NE + 255) / 256, 256, 0, stream>>>(row, cnt);
    scan_rowptr<<<1, 1024, 0, stream>>>(cnt, rowptr, rowcur);
    scatter_edges<<<(NE + 255) / 256, 256, 0, stream>>>(row, col, vals, rowcur, ecol, ew);

    const int MT = (NN + 127) / 128;  // 391

    // layer 1: [50000,512] @ [512,256]
    gemm_bf16<<<dim3(MT, 2), 256, 0, stream>>>(Xb, Wt1, S, NN, 256, 512);
    spmm_gather_bf16<256, true><<<(NN + 7) / 8, 256, 0, stream>>>(S, rowptr, ecol, ew, b1, Hb);
    // layer 2
    gemm_bf16<<<dim3(MT, 2), 256, 0, stream>>>(Hb, Wt2, S, NN, 256, 256);
    spmm_gather_bf16<256, true><<<(NN + 7) / 8, 256, 0, stream>>>(S, rowptr, ecol, ew, b2, Hb);
    // layer 3
    gemm_bf16<<<dim3(MT, 1), 256, 0, stream>>>(Hb, Wt3, S, NN, 128, 256);
    spmm_gather_bf16<128, true><<<(NN + 15) / 16, 256, 0, stream>>>(S, rowptr, ecol, ew, b3, Hb);
    // layer 4
    gemm_bf16<<<dim3(MT, 1), 256, 0, stream>>>(Hb, Wt4, S, NN, 128, 128);
    spmm_gather_bf16<128, false><<<(NN + 15) / 16, 256, 0, stream>>>(S, rowptr, ecol, ew, b4, out);
}

// Round 5
// 427.862 us; speedup vs baseline: 20.3044x; 1.2324x over previous
//
#include <hip/hip_runtime.h>
#include <hip/hip_bf16.h>

#define NN 50000
#define NE 800000
#define LEAKY 0.25f
#define SCAN_NB ((NN + 255) / 256)   // 196

typedef __attribute__((ext_vector_type(8))) short bf16x8;
typedef __attribute__((ext_vector_type(8))) ushort u16x8;
typedef __attribute__((ext_vector_type(4))) float f32x4;

static __device__ __forceinline__ ushort f2bf(float f) {
    union { __hip_bfloat16 h; ushort u; } cv;
    cv.h = __float2bfloat16(f);
    return cv.u;
}
static __device__ __forceinline__ float bf2f(ushort u) {
    union { unsigned u; float f; } cv;
    cv.u = ((unsigned)u) << 16;
    return cv.f;
}

// ---------------- casts ----------------
__global__ void cast_bf16_vec(const float4* __restrict__ in, ushort4* __restrict__ out, int n4) {
    int i = blockIdx.x * blockDim.x + threadIdx.x;
    if (i >= n4) return;
    float4 v = in[i];
    ushort4 o;
    o.x = f2bf(v.x); o.y = f2bf(v.y); o.z = f2bf(v.z); o.w = f2bf(v.w);
    out[i] = o;
}

__global__ void cast_transpose_w(const float* __restrict__ W, ushort* __restrict__ Wt, int K, int N) {
    int idx = blockIdx.x * blockDim.x + threadIdx.x;
    if (idx >= K * N) return;
    int k = idx / N, n = idx % N;
    Wt[n * K + k] = f2bf(W[idx]);
}

// ---------------- bf16 MFMA GEMM: C[M,N] = A[M,K] @ Bt[N,K]^T, C in bf16 ----------------
__global__ __launch_bounds__(256) void gemm_bf16(
    const ushort* __restrict__ A, const ushort* __restrict__ Bt,
    ushort* __restrict__ C, int M, int N, int K)
{
    __shared__ ushort As[128 * 32];
    __shared__ ushort Bs[128 * 32];
    const int tid  = threadIdx.x;
    const int lane = tid & 63;
    const int wid  = tid >> 6;
    const int wr = wid >> 1, wc = wid & 1;
    const int m0 = blockIdx.x * 128;
    const int n0 = blockIdx.y * 128;

    int ar1 = m0 + (tid >> 2);      if (ar1 >= M) ar1 = M - 1;
    int ar2 = m0 + 64 + (tid >> 2); if (ar2 >= M) ar2 = M - 1;
    const int br1 = n0 + (tid >> 2);
    const int br2 = br1 + 64;
    const int ccol = (tid & 3) * 8;

    const ushort* gA1 = A + (size_t)ar1 * K + ccol;
    const ushort* gA2 = A + (size_t)ar2 * K + ccol;
    const ushort* gB1 = Bt + (size_t)br1 * K + ccol;
    const ushort* gB2 = Bt + (size_t)br2 * K + ccol;

    char* ldsA = (char*)As + wid * 1024;
    char* ldsB = (char*)Bs + wid * 1024;

    const int fr = lane & 15;
    const int fq = lane >> 4;

    const ushort* fragA = As + (wr * 64 + fr) * 32 + fq * 8;
    const ushort* fragB = Bs + (wc * 64 + fr) * 32 + fq * 8;

    f32x4 acc[4][4];
    #pragma unroll
    for (int i = 0; i < 4; ++i)
        #pragma unroll
        for (int j = 0; j < 4; ++j)
            acc[i][j] = {0.f, 0.f, 0.f, 0.f};

    for (int k0 = 0; k0 < K; k0 += 32) {
        __builtin_amdgcn_global_load_lds((const __attribute__((address_space(1))) void*)(gA1 + k0),
                                         (__attribute__((address_space(3))) void*)(ldsA), 16, 0, 0);
        __builtin_amdgcn_global_load_lds((const __attribute__((address_space(1))) void*)(gA2 + k0),
                                         (__attribute__((address_space(3))) void*)(ldsA + 4096), 16, 0, 0);
        __builtin_amdgcn_global_load_lds((const __attribute__((address_space(1))) void*)(gB1 + k0),
                                         (__attribute__((address_space(3))) void*)(ldsB), 16, 0, 0);
        __builtin_amdgcn_global_load_lds((const __attribute__((address_space(1))) void*)(gB2 + k0),
                                         (__attribute__((address_space(3))) void*)(ldsB + 4096), 16, 0, 0);
        __syncthreads();

        bf16x8 a[4], b[4];
        #pragma unroll
        for (int mi = 0; mi < 4; ++mi) a[mi] = *(const bf16x8*)(fragA + mi * 16 * 32);
        #pragma unroll
        for (int ni = 0; ni < 4; ++ni) b[ni] = *(const bf16x8*)(fragB + ni * 16 * 32);
        #pragma unroll
        for (int mi = 0; mi < 4; ++mi)
            #pragma unroll
            for (int ni = 0; ni < 4; ++ni)
                acc[mi][ni] = __builtin_amdgcn_mfma_f32_16x16x32_bf16(a[mi], b[ni], acc[mi][ni], 0, 0, 0);
        __syncthreads();
    }

    #pragma unroll
    for (int mi = 0; mi < 4; ++mi) {
        #pragma unroll
        for (int j = 0; j < 4; ++j) {
            int row = m0 + wr * 64 + mi * 16 + fq * 4 + j;
            if (row >= M) continue;
            #pragma unroll
            for (int ni = 0; ni < 4; ++ni) {
                int colg = n0 + wc * 64 + ni * 16 + fr;
                C[(size_t)row * N + colg] = f2bf(acc[mi][ni][j]);
            }
        }
    }
}

// ---------------- CSR construction ----------------
__global__ void hist_rows(const int* __restrict__ row, int* __restrict__ cnt) {
    int e = blockIdx.x * blockDim.x + threadIdx.x;
    if (e < NE) atomicAdd(&cnt[row[e]], 1);
}

// phase 1: per-block sums of cnt (256 elems per block)
__global__ void scan_bsum(const int* __restrict__ cnt, int* __restrict__ bsum) {
    int i = blockIdx.x * 256 + threadIdx.x;
    int v = (i < NN) ? cnt[i] : 0;
    #pragma unroll
    for (int off = 32; off >= 1; off >>= 1) v += __shfl_down(v, off);
    __shared__ int ws[4];
    if ((threadIdx.x & 63) == 0) ws[threadIdx.x >> 6] = v;
    __syncthreads();
    if (threadIdx.x == 0) bsum[blockIdx.x] = ws[0] + ws[1] + ws[2] + ws[3];
}

// phase 2: one block scans the block sums (SCAN_NB <= 256)
__global__ void scan_boff(const int* __restrict__ bsum, int* __restrict__ boff,
                          int* __restrict__ rowptr) {
    __shared__ int s[256];
    int t = threadIdx.x;
    int v = (t < SCAN_NB) ? bsum[t] : 0;
    s[t] = v;
    __syncthreads();
    #pragma unroll
    for (int off = 1; off < 256; off <<= 1) {
        int u = (t >= off) ? s[t - off] : 0;
        __syncthreads();
        s[t] += u;
        __syncthreads();
    }
    if (t < SCAN_NB) boff[t] = s[t] - v;       // exclusive block offset
    if (t == 255) rowptr[NN] = s[255];         // grand total
}

// phase 3: per-block exclusive scan + offset -> rowptr, rowcur
__global__ void scan_write(const int* __restrict__ cnt, const int* __restrict__ boff,
                           int* __restrict__ rowptr, int* __restrict__ rowcur) {
    __shared__ int s[256];
    int b = blockIdx.x;
    int t = threadIdx.x;
    int i = b * 256 + t;
    int v = (i < NN) ? cnt[i] : 0;
    s[t] = v;
    __syncthreads();
    #pragma unroll
    for (int off = 1; off < 256; off <<= 1) {
        int u = (t >= off) ? s[t - off] : 0;
        __syncthreads();
        s[t] += u;
        __syncthreads();
    }
    if (i < NN) {
        int ex = boff[b] + s[t] - v;
        rowptr[i] = ex;
        rowcur[i] = ex;
    }
}

__global__ void scatter_edges(const int* __restrict__ row, const int* __restrict__ col,
                              const float* __restrict__ vals,
                              int* __restrict__ rowcur,
                              int* __restrict__ ecol, float* __restrict__ ew) {
    int e = blockIdx.x * blockDim.x + threadIdx.x;
    if (e < NE) {
        int p = atomicAdd(&rowcur[row[e]], 1);
        ecol[p] = col[e];
        ew[p]   = vals[e];
    }
}

// ---------------- SpMM gather (bf16 support) + bias + leakyReLU fused ----------------
template<int DIM, bool OUT_BF16>
__global__ void spmm_gather_bf16(const ushort* __restrict__ support,
                                 const int* __restrict__ rowptr,
                                 const int* __restrict__ ecol,
                                 const float* __restrict__ ew,
                                 const float* __restrict__ bias,
                                 void* __restrict__ out) {
    constexpr int LPR = DIM / 8;        // lanes per row (32 or 16)
    constexpr int RPB = 256 / LPR;      // rows per block (8 or 16)
    int r = blockIdx.x * RPB + threadIdx.x / LPR;
    int lane = threadIdx.x % LPR;
    if (r >= NN) return;
    int s = rowptr[r], e = rowptr[r + 1];
    float acc[8] = {};
    for (int i = s; i < e; ++i) {
        int c = ecol[i];
        float w = ew[i];
        u16x8 v = *(const u16x8*)(support + (size_t)c * DIM + lane * 8);
        #pragma unroll
        for (int j = 0; j < 8; ++j) acc[j] += w * bf2f(v[j]);
    }
    const float4 bb0 = ((const float4*)bias)[lane * 2];
    const float4 bb1 = ((const float4*)bias)[lane * 2 + 1];
    acc[0] += bb0.x; acc[1] += bb0.y; acc[2] += bb0.z; acc[3] += bb0.w;
    acc[4] += bb1.x; acc[5] += bb1.y; acc[6] += bb1.z; acc[7] += bb1.w;
    #pragma unroll
    for (int j = 0; j < 8; ++j) acc[j] = (acc[j] >= 0.f) ? acc[j] : LEAKY * acc[j];
    if (OUT_BF16) {
        ushort4 o0, o1;
        o0.x = f2bf(acc[0]); o0.y = f2bf(acc[1]); o0.z = f2bf(acc[2]); o0.w = f2bf(acc[3]);
        o1.x = f2bf(acc[4]); o1.y = f2bf(acc[5]); o1.z = f2bf(acc[6]); o1.w = f2bf(acc[7]);
        ((ushort4*)out)[(size_t)r * LPR * 2 + lane * 2]     = o0;
        ((ushort4*)out)[(size_t)r * LPR * 2 + lane * 2 + 1] = o1;
    } else {
        float4 f0 = {acc[0], acc[1], acc[2], acc[3]};
        float4 f1 = {acc[4], acc[5], acc[6], acc[7]};
        ((float4*)out)[(size_t)r * LPR * 2 + lane * 2]     = f0;
        ((float4*)out)[(size_t)r * LPR * 2 + lane * 2 + 1] = f1;
    }
}

extern "C" void kernel_launch(void* const* d_in, const int* in_sizes, int n_in,
                              void* d_out, int out_size, void* d_ws, size_t ws_size,
                              hipStream_t stream) {
    const float* x    = (const float*)d_in[0];
    const int*   row  = (const int*)d_in[1];
    const int*   col  = (const int*)d_in[2];
    const float* vals = (const float*)d_in[3];
    const float* W1 = (const float*)d_in[4];  const float* b1 = (const float*)d_in[5];
    const float* W2 = (const float*)d_in[6];  const float* b2 = (const float*)d_in[7];
    const float* W3 = (const float*)d_in[8];  const float* b3 = (const float*)d_in[9];
    const float* W4 = (const float*)d_in[10]; const float* b4 = (const float*)d_in[11];

    // workspace: Xb (NN*512 u16; Hb aliases) | S (NN*256 u16) | Wt | CSR | scan tmp
    ushort* Xb = (ushort*)d_ws;
    ushort* Hb = Xb;                        // Xb dead after layer-1 GEMM
    ushort* S  = Xb + (size_t)NN * 512;
    ushort* Wt1 = S + (size_t)NN * 256;
    ushort* Wt2 = Wt1 + 512 * 256;
    ushort* Wt3 = Wt2 + 256 * 256;
    ushort* Wt4 = Wt3 + 256 * 128;
    int* cnt    = (int*)(Wt4 + 128 * 128);
    int* rowptr = cnt + NN;
    int* rowcur = rowptr + (NN + 1);
    int* ecol   = rowcur + (NN + 1);
    float* ew   = (float*)(ecol + NE);
    int* bsum   = (int*)(ew + NE);
    int* boff   = bsum + SCAN_NB;
    float* out  = (float*)d_out;

    // ---- casts ----
    {
        int n4 = NN * 512 / 4;
        cast_bf16_vec<<<(n4 + 255) / 256, 256, 0, stream>>>((const float4*)x, (ushort4*)Xb, n4);
        cast_transpose_w<<<(512 * 256 + 255) / 256, 256, 0, stream>>>(W1, Wt1, 512, 256);
        cast_transpose_w<<<(256 * 256 + 255) / 256, 256, 0, stream>>>(W2, Wt2, 256, 256);
        cast_transpose_w<<<(256 * 128 + 255) / 256, 256, 0, stream>>>(W3, Wt3, 256, 128);
        cast_transpose_w<<<(128 * 128 + 255) / 256, 256, 0, stream>>>(W4, Wt4, 128, 128);
    }

    // ---- build CSR (hierarchical scan) ----
    hipMemsetAsync(cnt, 0, NN * sizeof(int), stream);
    hist_rows<<<(NE + 255) / 256, 256, 0, stream>>>(row, cnt);
    scan_bsum<<<SCAN_NB, 256, 0, stream>>>(cnt, bsum);
    scan_boff<<<1, 256, 0, stream>>>(bsum, boff, rowptr);
    scan_write<<<SCAN_NB, 256, 0, stream>>>(cnt, boff, rowptr, rowcur);
    scatter_edges<<<(NE + 255) / 256, 256, 0, stream>>>(row, col, vals, rowcur, ecol, ew);

    const int MT = (NN + 127) / 128;  // 391

    // layer 1: [50000,512] @ [512,256]
    gemm_bf16<<<dim3(MT, 2), 256, 0, stream>>>(Xb, Wt1, S, NN, 256, 512);
    spmm_gather_bf16<256, true><<<(NN + 7) / 8, 256, 0, stream>>>(S, rowptr, ecol, ew, b1, Hb);
    // layer 2
    gemm_bf16<<<dim3(MT, 2), 256, 0, stream>>>(Hb, Wt2, S, NN, 256, 256);
    spmm_gather_bf16<256, true><<<(NN + 7) / 8, 256, 0, stream>>>(S, rowptr, ecol, ew, b2, Hb);
    // layer 3
    gemm_bf16<<<dim3(MT, 1), 256, 0, stream>>>(Hb, Wt3, S, NN, 128, 256);
    spmm_gather_bf16<128, true><<<(NN + 15) / 16, 256, 0, stream>>>(S, rowptr, ecol, ew, b3, Hb);
    // layer 4
    gemm_bf16<<<dim3(MT, 1), 256, 0, stream>>>(Hb, Wt4, S, NN, 128, 128);
    spmm_gather_bf16<128, false><<<(NN + 15) / 16, 256, 0, stream>>>(S, rowptr, ecol, ew, b4, out);
}

// Round 6
// 390.592 us; speedup vs baseline: 22.2418x; 1.0954x over previous
//
#include <hip/hip_runtime.h>
#include <hip/hip_bf16.h>

#define NN 50000
#define NE 800000
#define LEAKY 0.25f
#define SCAN_NB ((NN + 255) / 256)   // 196

typedef __attribute__((ext_vector_type(8))) short bf16x8;
typedef __attribute__((ext_vector_type(8))) ushort u16x8;
typedef __attribute__((ext_vector_type(4))) float f32x4;

static __device__ __forceinline__ ushort f2bf(float f) {
    union { __hip_bfloat16 h; ushort u; } cv;
    cv.h = __float2bfloat16(f);
    return cv.u;
}
static __device__ __forceinline__ float bf2f(ushort u) {
    union { unsigned u; float f; } cv;
    cv.u = ((unsigned)u) << 16;
    return cv.f;
}

// ---------------- casts ----------------
__global__ void cast_bf16_x8(const float4* __restrict__ in, u16x8* __restrict__ out, int n8) {
    int i = blockIdx.x * blockDim.x + threadIdx.x;
    if (i >= n8) return;
    float4 v0 = in[i * 2];
    float4 v1 = in[i * 2 + 1];
    u16x8 o;
    o[0] = f2bf(v0.x); o[1] = f2bf(v0.y); o[2] = f2bf(v0.z); o[3] = f2bf(v0.w);
    o[4] = f2bf(v1.x); o[5] = f2bf(v1.y); o[6] = f2bf(v1.z); o[7] = f2bf(v1.w);
    out[i] = o;
}

__global__ void cast_transpose_w(const float* __restrict__ W, ushort* __restrict__ Wt, int K, int N) {
    int idx = blockIdx.x * blockDim.x + threadIdx.x;
    if (idx >= K * N) return;
    int k = idx / N, n = idx % N;
    Wt[n * K + k] = f2bf(W[idx]);
}

// ---------------- bf16 MFMA GEMM: C[M,N] = A[M,K] @ Bt[N,K]^T, C in bf16 ----------------
__global__ __launch_bounds__(256) void gemm_bf16(
    const ushort* __restrict__ A, const ushort* __restrict__ Bt,
    ushort* __restrict__ C, int M, int N, int K)
{
    __shared__ ushort As[128 * 32];
    __shared__ ushort Bs[128 * 32];
    const int tid  = threadIdx.x;
    const int lane = tid & 63;
    const int wid  = tid >> 6;
    const int wr = wid >> 1, wc = wid & 1;
    const int m0 = blockIdx.x * 128;
    const int n0 = blockIdx.y * 128;

    int ar1 = m0 + (tid >> 2);      if (ar1 >= M) ar1 = M - 1;
    int ar2 = m0 + 64 + (tid >> 2); if (ar2 >= M) ar2 = M - 1;
    const int br1 = n0 + (tid >> 2);
    const int br2 = br1 + 64;
    const int ccol = (tid & 3) * 8;

    const ushort* gA1 = A + (size_t)ar1 * K + ccol;
    const ushort* gA2 = A + (size_t)ar2 * K + ccol;
    const ushort* gB1 = Bt + (size_t)br1 * K + ccol;
    const ushort* gB2 = Bt + (size_t)br2 * K + ccol;

    char* ldsA = (char*)As + wid * 1024;
    char* ldsB = (char*)Bs + wid * 1024;

    const int fr = lane & 15;
    const int fq = lane >> 4;

    const ushort* fragA = As + (wr * 64 + fr) * 32 + fq * 8;
    const ushort* fragB = Bs + (wc * 64 + fr) * 32 + fq * 8;

    f32x4 acc[4][4];
    #pragma unroll
    for (int i = 0; i < 4; ++i)
        #pragma unroll
        for (int j = 0; j < 4; ++j)
            acc[i][j] = {0.f, 0.f, 0.f, 0.f};

    for (int k0 = 0; k0 < K; k0 += 32) {
        __builtin_amdgcn_global_load_lds((const __attribute__((address_space(1))) void*)(gA1 + k0),
                                         (__attribute__((address_space(3))) void*)(ldsA), 16, 0, 0);
        __builtin_amdgcn_global_load_lds((const __attribute__((address_space(1))) void*)(gA2 + k0),
                                         (__attribute__((address_space(3))) void*)(ldsA + 4096), 16, 0, 0);
        __builtin_amdgcn_global_load_lds((const __attribute__((address_space(1))) void*)(gB1 + k0),
                                         (__attribute__((address_space(3))) void*)(ldsB), 16, 0, 0);
        __builtin_amdgcn_global_load_lds((const __attribute__((address_space(1))) void*)(gB2 + k0),
                                         (__attribute__((address_space(3))) void*)(ldsB + 4096), 16, 0, 0);
        __syncthreads();

        bf16x8 a[4], b[4];
        #pragma unroll
        for (int mi = 0; mi < 4; ++mi) a[mi] = *(const bf16x8*)(fragA + mi * 16 * 32);
        #pragma unroll
        for (int ni = 0; ni < 4; ++ni) b[ni] = *(const bf16x8*)(fragB + ni * 16 * 32);
        #pragma unroll
        for (int mi = 0; mi < 4; ++mi)
            #pragma unroll
            for (int ni = 0; ni < 4; ++ni)
                acc[mi][ni] = __builtin_amdgcn_mfma_f32_16x16x32_bf16(a[mi], b[ni], acc[mi][ni], 0, 0, 0);
        __syncthreads();
    }

    #pragma unroll
    for (int mi = 0; mi < 4; ++mi) {
        #pragma unroll
        for (int j = 0; j < 4; ++j) {
            int row = m0 + wr * 64 + mi * 16 + fq * 4 + j;
            if (row >= M) continue;
            #pragma unroll
            for (int ni = 0; ni < 4; ++ni) {
                int colg = n0 + wc * 64 + ni * 16 + fr;
                C[(size_t)row * N + colg] = f2bf(acc[mi][ni][j]);
            }
        }
    }
}

// ---------------- CSR construction ----------------
__global__ void hist_rows(const int* __restrict__ row, int* __restrict__ cnt) {
    int e = blockIdx.x * blockDim.x + threadIdx.x;
    if (e < NE) atomicAdd(&cnt[row[e]], 1);
}

__global__ void scan_bsum(const int* __restrict__ cnt, int* __restrict__ bsum) {
    int i = blockIdx.x * 256 + threadIdx.x;
    int v = (i < NN) ? cnt[i] : 0;
    #pragma unroll
    for (int off = 32; off >= 1; off >>= 1) v += __shfl_down(v, off);
    __shared__ int ws[4];
    if ((threadIdx.x & 63) == 0) ws[threadIdx.x >> 6] = v;
    __syncthreads();
    if (threadIdx.x == 0) bsum[blockIdx.x] = ws[0] + ws[1] + ws[2] + ws[3];
}

__global__ void scan_boff(const int* __restrict__ bsum, int* __restrict__ boff,
                          int* __restrict__ rowptr) {
    __shared__ int s[256];
    int t = threadIdx.x;
    int v = (t < SCAN_NB) ? bsum[t] : 0;
    s[t] = v;
    __syncthreads();
    #pragma unroll
    for (int off = 1; off < 256; off <<= 1) {
        int u = (t >= off) ? s[t - off] : 0;
        __syncthreads();
        s[t] += u;
        __syncthreads();
    }
    if (t < SCAN_NB) boff[t] = s[t] - v;
    if (t == 255) rowptr[NN] = s[255];
}

__global__ void scan_write(const int* __restrict__ cnt, const int* __restrict__ boff,
                           int* __restrict__ rowptr, int* __restrict__ rowcur) {
    __shared__ int s[256];
    int b = blockIdx.x;
    int t = threadIdx.x;
    int i = b * 256 + t;
    int v = (i < NN) ? cnt[i] : 0;
    s[t] = v;
    __syncthreads();
    #pragma unroll
    for (int off = 1; off < 256; off <<= 1) {
        int u = (t >= off) ? s[t - off] : 0;
        __syncthreads();
        s[t] += u;
        __syncthreads();
    }
    if (i < NN) {
        int ex = boff[b] + s[t] - v;
        rowptr[i] = ex;
        rowcur[i] = ex;
    }
}

// pack (col, weight) into one 8B word: low32 = col, high32 = f32 bits of weight
__global__ void scatter_edges(const int* __restrict__ row, const int* __restrict__ col,
                              const float* __restrict__ vals,
                              int* __restrict__ rowcur,
                              unsigned long long* __restrict__ epack) {
    int e = blockIdx.x * blockDim.x + threadIdx.x;
    if (e < NE) {
        int p = atomicAdd(&rowcur[row[e]], 1);
        unsigned long long pk = ((unsigned long long)__float_as_uint(vals[e]) << 32) | (unsigned)col[e];
        epack[p] = pk;
    }
}

// ---------------- SpMM gather (bf16 support) + bias + leakyReLU fused ----------------
// 2-edge unroll, dual accumulators to break FMA dependency chain.
template<int DIM, bool OUT_BF16>
__global__ void spmm_gather_bf16(const ushort* __restrict__ support,
                                 const int* __restrict__ rowptr,
                                 const unsigned long long* __restrict__ epack,
                                 const float* __restrict__ bias,
                                 void* __restrict__ out) {
    constexpr int LPR = DIM / 8;        // lanes per row (32 or 16)
    constexpr int RPB = 256 / LPR;      // rows per block (8 or 16)
    int r = blockIdx.x * RPB + threadIdx.x / LPR;
    int lane = threadIdx.x % LPR;
    if (r >= NN) return;
    int s = rowptr[r], e = rowptr[r + 1];
    float acc0[8] = {}, acc1[8] = {};
    int i = s;
    for (; i + 1 < e; i += 2) {
        unsigned long long p0 = epack[i];
        unsigned long long p1 = epack[i + 1];
        int c0 = (int)(unsigned)p0;
        int c1 = (int)(unsigned)p1;
        float w0 = __uint_as_float((unsigned)(p0 >> 32));
        float w1 = __uint_as_float((unsigned)(p1 >> 32));
        u16x8 v0 = *(const u16x8*)(support + (size_t)c0 * DIM + lane * 8);
        u16x8 v1 = *(const u16x8*)(support + (size_t)c1 * DIM + lane * 8);
        #pragma unroll
        for (int j = 0; j < 8; ++j) acc0[j] += w0 * bf2f(v0[j]);
        #pragma unroll
        for (int j = 0; j < 8; ++j) acc1[j] += w1 * bf2f(v1[j]);
    }
    if (i < e) {
        unsigned long long p0 = epack[i];
        int c0 = (int)(unsigned)p0;
        float w0 = __uint_as_float((unsigned)(p0 >> 32));
        u16x8 v0 = *(const u16x8*)(support + (size_t)c0 * DIM + lane * 8);
        #pragma unroll
        for (int j = 0; j < 8; ++j) acc0[j] += w0 * bf2f(v0[j]);
    }
    const float4 bb0 = ((const float4*)bias)[lane * 2];
    const float4 bb1 = ((const float4*)bias)[lane * 2 + 1];
    float acc[8];
    #pragma unroll
    for (int j = 0; j < 8; ++j) acc[j] = acc0[j] + acc1[j];
    acc[0] += bb0.x; acc[1] += bb0.y; acc[2] += bb0.z; acc[3] += bb0.w;
    acc[4] += bb1.x; acc[5] += bb1.y; acc[6] += bb1.z; acc[7] += bb1.w;
    #pragma unroll
    for (int j = 0; j < 8; ++j) acc[j] = (acc[j] >= 0.f) ? acc[j] : LEAKY * acc[j];
    if (OUT_BF16) {
        ushort4 o0, o1;
        o0.x = f2bf(acc[0]); o0.y = f2bf(acc[1]); o0.z = f2bf(acc[2]); o0.w = f2bf(acc[3]);
        o1.x = f2bf(acc[4]); o1.y = f2bf(acc[5]); o1.z = f2bf(acc[6]); o1.w = f2bf(acc[7]);
        ((ushort4*)out)[(size_t)r * LPR * 2 + lane * 2]     = o0;
        ((ushort4*)out)[(size_t)r * LPR * 2 + lane * 2 + 1] = o1;
    } else {
        float4 f0 = {acc[0], acc[1], acc[2], acc[3]};
        float4 f1 = {acc[4], acc[5], acc[6], acc[7]};
        ((float4*)out)[(size_t)r * LPR * 2 + lane * 2]     = f0;
        ((float4*)out)[(size_t)r * LPR * 2 + lane * 2 + 1] = f1;
    }
}

extern "C" void kernel_launch(void* const* d_in, const int* in_sizes, int n_in,
                              void* d_out, int out_size, void* d_ws, size_t ws_size,
                              hipStream_t stream) {
    const float* x    = (const float*)d_in[0];
    const int*   row  = (const int*)d_in[1];
    const int*   col  = (const int*)d_in[2];
    const float* vals = (const float*)d_in[3];
    const float* W1 = (const float*)d_in[4];  const float* b1 = (const float*)d_in[5];
    const float* W2 = (const float*)d_in[6];  const float* b2 = (const float*)d_in[7];
    const float* W3 = (const float*)d_in[8];  const float* b3 = (const float*)d_in[9];
    const float* W4 = (const float*)d_in[10]; const float* b4 = (const float*)d_in[11];

    // workspace: Xb (NN*512 u16; Hb aliases) | S (NN*256 u16) | Wt | cnt/rowptr/rowcur | epack | scan tmp
    ushort* Xb = (ushort*)d_ws;
    ushort* Hb = Xb;
    ushort* S  = Xb + (size_t)NN * 512;
    ushort* Wt1 = S + (size_t)NN * 256;
    ushort* Wt2 = Wt1 + 512 * 256;
    ushort* Wt3 = Wt2 + 256 * 256;
    ushort* Wt4 = Wt3 + 256 * 128;
    int* cnt    = (int*)(Wt4 + 128 * 128);
    int* rowptr = cnt + NN;
    int* rowcur = rowptr + (NN + 1);
    int* pend   = rowcur + (NN + 1);   // 600008 B from cnt start: 8B aligned
    unsigned long long* epack = (unsigned long long*)pend;
    int* bsum   = (int*)(epack + NE);
    int* boff   = bsum + SCAN_NB;
    float* out  = (float*)d_out;

    // ---- casts ----
    {
        int n8 = NN * 512 / 8;
        cast_bf16_x8<<<(n8 + 255) / 256, 256, 0, stream>>>((const float4*)x, (u16x8*)Xb, n8);
        cast_transpose_w<<<(512 * 256 + 255) / 256, 256, 0, stream>>>(W1, Wt1, 512, 256);
        cast_transpose_w<<<(256 * 256 + 255) / 256, 256, 0, stream>>>(W2, Wt2, 256, 256);
        cast_transpose_w<<<(256 * 128 + 255) / 256, 256, 0, stream>>>(W3, Wt3, 256, 128);
        cast_transpose_w<<<(128 * 128 + 255) / 256, 256, 0, stream>>>(W4, Wt4, 128, 128);
    }

    // ---- build CSR ----
    hipMemsetAsync(cnt, 0, NN * sizeof(int), stream);
    hist_rows<<<(NE + 255) / 256, 256, 0, stream>>>(row, cnt);
    scan_bsum<<<SCAN_NB, 256, 0, stream>>>(cnt, bsum);
    scan_boff<<<1, 256, 0, stream>>>(bsum, boff, rowptr);
    scan_write<<<SCAN_NB, 256, 0, stream>>>(cnt, boff, rowptr, rowcur);
    scatter_edges<<<(NE + 255) / 256, 256, 0, stream>>>(row, col, vals, rowcur, epack);

    const int MT = (NN + 127) / 128;  // 391

    // layer 1: [50000,512] @ [512,256]
    gemm_bf16<<<dim3(MT, 2), 256, 0, stream>>>(Xb, Wt1, S, NN, 256, 512);
    spmm_gather_bf16<256, true><<<(NN + 7) / 8, 256, 0, stream>>>(S, rowptr, epack, b1, Hb);
    // layer 2
    gemm_bf16<<<dim3(MT, 2), 256, 0, stream>>>(Hb, Wt2, S, NN, 256, 256);
    spmm_gather_bf16<256, true><<<(NN + 7) / 8, 256, 0, stream>>>(S, rowptr, epack, b2, Hb);
    // layer 3
    gemm_bf16<<<dim3(MT, 1), 256, 0, stream>>>(Hb, Wt3, S, NN, 128, 256);
    spmm_gather_bf16<128, true><<<(NN + 15) / 16, 256, 0, stream>>>(S, rowptr, epack, b3, Hb);
    // layer 4
    gemm_bf16<<<dim3(MT, 1), 256, 0, stream>>>(Hb, Wt4, S, NN, 128, 128);
    spmm_gather_bf16<128, false><<<(NN + 15) / 16, 256, 0, stream>>>(S, rowptr, epack, b4, out);
}

// Round 7
// 377.127 us; speedup vs baseline: 23.0359x; 1.0357x over previous
//
#include <hip/hip_runtime.h>
#include <hip/hip_bf16.h>

#define NN 50000
#define NE 800000
#define LEAKY 0.25f
#define SCAN_NB ((NN + 255) / 256)   // 196

typedef __attribute__((ext_vector_type(8))) short bf16x8;
typedef __attribute__((ext_vector_type(8))) ushort u16x8;
typedef __attribute__((ext_vector_type(4))) float f32x4;
typedef unsigned long long ull;

static __device__ __forceinline__ ushort f2bf(float f) {
    union { __hip_bfloat16 h; ushort u; } cv;
    cv.h = __float2bfloat16(f);
    return cv.u;
}
static __device__ __forceinline__ float bf2f(ushort u) {
    union { unsigned u; float f; } cv;
    cv.u = ((unsigned)u) << 16;
    return cv.f;
}

// ---------------- casts ----------------
__global__ void cast_bf16_x8(const float4* __restrict__ in, u16x8* __restrict__ out, int n8) {
    int i = blockIdx.x * blockDim.x + threadIdx.x;
    if (i >= n8) return;
    float4 v0 = in[i * 2];
    float4 v1 = in[i * 2 + 1];
    u16x8 o;
    o[0] = f2bf(v0.x); o[1] = f2bf(v0.y); o[2] = f2bf(v0.z); o[3] = f2bf(v0.w);
    o[4] = f2bf(v1.x); o[5] = f2bf(v1.y); o[6] = f2bf(v1.z); o[7] = f2bf(v1.w);
    out[i] = o;
}

__global__ void cast_transpose_w(const float* __restrict__ W, ushort* __restrict__ Wt, int K, int N) {
    int idx = blockIdx.x * blockDim.x + threadIdx.x;
    if (idx >= K * N) return;
    int k = idx / N, n = idx % N;
    Wt[n * K + k] = f2bf(W[idx]);
}

// ---------------- bf16 MFMA GEMM: C[M,N] = A[M,K] @ Bt[N,K]^T, C in bf16 ----------------
__global__ __launch_bounds__(256) void gemm_bf16(
    const ushort* __restrict__ A, const ushort* __restrict__ Bt,
    ushort* __restrict__ C, int M, int N, int K)
{
    __shared__ ushort As[128 * 32];
    __shared__ ushort Bs[128 * 32];
    const int tid  = threadIdx.x;
    const int lane = tid & 63;
    const int wid  = tid >> 6;
    const int wr = wid >> 1, wc = wid & 1;
    const int m0 = blockIdx.x * 128;
    const int n0 = blockIdx.y * 128;

    int ar1 = m0 + (tid >> 2);      if (ar1 >= M) ar1 = M - 1;
    int ar2 = m0 + 64 + (tid >> 2); if (ar2 >= M) ar2 = M - 1;
    const int br1 = n0 + (tid >> 2);
    const int br2 = br1 + 64;
    const int ccol = (tid & 3) * 8;

    const ushort* gA1 = A + (size_t)ar1 * K + ccol;
    const ushort* gA2 = A + (size_t)ar2 * K + ccol;
    const ushort* gB1 = Bt + (size_t)br1 * K + ccol;
    const ushort* gB2 = Bt + (size_t)br2 * K + ccol;

    char* ldsA = (char*)As + wid * 1024;
    char* ldsB = (char*)Bs + wid * 1024;

    const int fr = lane & 15;
    const int fq = lane >> 4;

    const ushort* fragA = As + (wr * 64 + fr) * 32 + fq * 8;
    const ushort* fragB = Bs + (wc * 64 + fr) * 32 + fq * 8;

    f32x4 acc[4][4];
    #pragma unroll
    for (int i = 0; i < 4; ++i)
        #pragma unroll
        for (int j = 0; j < 4; ++j)
            acc[i][j] = {0.f, 0.f, 0.f, 0.f};

    for (int k0 = 0; k0 < K; k0 += 32) {
        __builtin_amdgcn_global_load_lds((const __attribute__((address_space(1))) void*)(gA1 + k0),
                                         (__attribute__((address_space(3))) void*)(ldsA), 16, 0, 0);
        __builtin_amdgcn_global_load_lds((const __attribute__((address_space(1))) void*)(gA2 + k0),
                                         (__attribute__((address_space(3))) void*)(ldsA + 4096), 16, 0, 0);
        __builtin_amdgcn_global_load_lds((const __attribute__((address_space(1))) void*)(gB1 + k0),
                                         (__attribute__((address_space(3))) void*)(ldsB), 16, 0, 0);
        __builtin_amdgcn_global_load_lds((const __attribute__((address_space(1))) void*)(gB2 + k0),
                                         (__attribute__((address_space(3))) void*)(ldsB + 4096), 16, 0, 0);
        __syncthreads();

        bf16x8 a[4], b[4];
        #pragma unroll
        for (int mi = 0; mi < 4; ++mi) a[mi] = *(const bf16x8*)(fragA + mi * 16 * 32);
        #pragma unroll
        for (int ni = 0; ni < 4; ++ni) b[ni] = *(const bf16x8*)(fragB + ni * 16 * 32);
        #pragma unroll
        for (int mi = 0; mi < 4; ++mi)
            #pragma unroll
            for (int ni = 0; ni < 4; ++ni)
                acc[mi][ni] = __builtin_amdgcn_mfma_f32_16x16x32_bf16(a[mi], b[ni], acc[mi][ni], 0, 0, 0);
        __syncthreads();
    }

    #pragma unroll
    for (int mi = 0; mi < 4; ++mi) {
        #pragma unroll
        for (int j = 0; j < 4; ++j) {
            int row = m0 + wr * 64 + mi * 16 + fq * 4 + j;
            if (row >= M) continue;
            #pragma unroll
            for (int ni = 0; ni < 4; ++ni) {
                int colg = n0 + wc * 64 + ni * 16 + fr;
                C[(size_t)row * N + colg] = f2bf(acc[mi][ni][j]);
            }
        }
    }
}

// ---------------- CSR construction ----------------
__global__ void hist_rows(const int* __restrict__ row, int* __restrict__ cnt) {
    int e = blockIdx.x * blockDim.x + threadIdx.x;
    if (e < NE) atomicAdd(&cnt[row[e]], 1);
}

__global__ void scan_bsum(const int* __restrict__ cnt, int* __restrict__ bsum) {
    int i = blockIdx.x * 256 + threadIdx.x;
    int v = (i < NN) ? cnt[i] : 0;
    #pragma unroll
    for (int off = 32; off >= 1; off >>= 1) v += __shfl_down(v, off);
    __shared__ int ws[4];
    if ((threadIdx.x & 63) == 0) ws[threadIdx.x >> 6] = v;
    __syncthreads();
    if (threadIdx.x == 0) bsum[blockIdx.x] = ws[0] + ws[1] + ws[2] + ws[3];
}

__global__ void scan_boff(const int* __restrict__ bsum, int* __restrict__ boff,
                          int* __restrict__ rowptr) {
    __shared__ int s[256];
    int t = threadIdx.x;
    int v = (t < SCAN_NB) ? bsum[t] : 0;
    s[t] = v;
    __syncthreads();
    #pragma unroll
    for (int off = 1; off < 256; off <<= 1) {
        int u = (t >= off) ? s[t - off] : 0;
        __syncthreads();
        s[t] += u;
        __syncthreads();
    }
    if (t < SCAN_NB) boff[t] = s[t] - v;
    if (t == 255) rowptr[NN] = s[255];
}

__global__ void scan_write(const int* __restrict__ cnt, const int* __restrict__ boff,
                           int* __restrict__ rowptr, int* __restrict__ rowcur) {
    __shared__ int s[256];
    int b = blockIdx.x;
    int t = threadIdx.x;
    int i = b * 256 + t;
    int v = (i < NN) ? cnt[i] : 0;
    s[t] = v;
    __syncthreads();
    #pragma unroll
    for (int off = 1; off < 256; off <<= 1) {
        int u = (t >= off) ? s[t - off] : 0;
        __syncthreads();
        s[t] += u;
        __syncthreads();
    }
    if (i < NN) {
        int ex = boff[b] + s[t] - v;
        rowptr[i] = ex;
        rowcur[i] = ex;
    }
}

// pack (col, weight) into one 8B word: low32 = col, high32 = f32 bits of weight
__global__ void scatter_edges(const int* __restrict__ row, const int* __restrict__ col,
                              const float* __restrict__ vals,
                              int* __restrict__ rowcur,
                              ull* __restrict__ epack) {
    int e = blockIdx.x * blockDim.x + threadIdx.x;
    if (e < NE) {
        int p = atomicAdd(&rowcur[row[e]], 1);
        ull pk = ((ull)__float_as_uint(vals[e]) << 32) | (unsigned)col[e];
        epack[p] = pk;
    }
}

// ---------------- SpMM gather (bf16 support) + bias + leakyReLU fused ----------------
// 4-edge unroll: 4 independent 16B gathers in flight per lane; 2 accumulator sets.
template<int DIM, bool OUT_BF16>
__global__ __launch_bounds__(256) void spmm_gather_bf16(
    const ushort* __restrict__ support,
    const int* __restrict__ rowptr,
    const ull* __restrict__ epack,
    const float* __restrict__ bias,
    void* __restrict__ out) {
    constexpr int LPR = DIM / 8;        // lanes per row (32 or 16)
    constexpr int RPB = 256 / LPR;      // rows per block (8 or 16)
    int r = blockIdx.x * RPB + threadIdx.x / LPR;
    int lane = threadIdx.x % LPR;
    if (r >= NN) return;
    int s = rowptr[r], e = rowptr[r + 1];
    float acc0[8] = {}, acc1[8] = {};
    int i = s;
    for (; i + 3 < e; i += 4) {
        ull p0 = epack[i];
        ull p1 = epack[i + 1];
        ull p2 = epack[i + 2];
        ull p3 = epack[i + 3];
        const u16x8* a0 = (const u16x8*)(support + (size_t)(unsigned)p0 * DIM) + lane;
        const u16x8* a1 = (const u16x8*)(support + (size_t)(unsigned)p1 * DIM) + lane;
        const u16x8* a2 = (const u16x8*)(support + (size_t)(unsigned)p2 * DIM) + lane;
        const u16x8* a3 = (const u16x8*)(support + (size_t)(unsigned)p3 * DIM) + lane;
        u16x8 v0 = *a0;
        u16x8 v1 = *a1;
        u16x8 v2 = *a2;
        u16x8 v3 = *a3;
        float w0 = __uint_as_float((unsigned)(p0 >> 32));
        float w1 = __uint_as_float((unsigned)(p1 >> 32));
        float w2 = __uint_as_float((unsigned)(p2 >> 32));
        float w3 = __uint_as_float((unsigned)(p3 >> 32));
        #pragma unroll
        for (int j = 0; j < 8; ++j) acc0[j] += w0 * bf2f(v0[j]);
        #pragma unroll
        for (int j = 0; j < 8; ++j) acc1[j] += w1 * bf2f(v1[j]);
        #pragma unroll
        for (int j = 0; j < 8; ++j) acc0[j] += w2 * bf2f(v2[j]);
        #pragma unroll
        for (int j = 0; j < 8; ++j) acc1[j] += w3 * bf2f(v3[j]);
    }
    for (; i < e; ++i) {
        ull p0 = epack[i];
        float w0 = __uint_as_float((unsigned)(p0 >> 32));
        u16x8 v0 = *((const u16x8*)(support + (size_t)(unsigned)p0 * DIM) + lane);
        #pragma unroll
        for (int j = 0; j < 8; ++j) acc0[j] += w0 * bf2f(v0[j]);
    }
    const float4 bb0 = ((const float4*)bias)[lane * 2];
    const float4 bb1 = ((const float4*)bias)[lane * 2 + 1];
    float acc[8];
    #pragma unroll
    for (int j = 0; j < 8; ++j) acc[j] = acc0[j] + acc1[j];
    acc[0] += bb0.x; acc[1] += bb0.y; acc[2] += bb0.z; acc[3] += bb0.w;
    acc[4] += bb1.x; acc[5] += bb1.y; acc[6] += bb1.z; acc[7] += bb1.w;
    #pragma unroll
    for (int j = 0; j < 8; ++j) acc[j] = (acc[j] >= 0.f) ? acc[j] : LEAKY * acc[j];
    if (OUT_BF16) {
        ushort4 o0, o1;
        o0.x = f2bf(acc[0]); o0.y = f2bf(acc[1]); o0.z = f2bf(acc[2]); o0.w = f2bf(acc[3]);
        o1.x = f2bf(acc[4]); o1.y = f2bf(acc[5]); o1.z = f2bf(acc[6]); o1.w = f2bf(acc[7]);
        ((ushort4*)out)[(size_t)r * LPR * 2 + lane * 2]     = o0;
        ((ushort4*)out)[(size_t)r * LPR * 2 + lane * 2 + 1] = o1;
    } else {
        float4 f0 = {acc[0], acc[1], acc[2], acc[3]};
        float4 f1 = {acc[4], acc[5], acc[6], acc[7]};
        ((float4*)out)[(size_t)r * LPR * 2 + lane * 2]     = f0;
        ((float4*)out)[(size_t)r * LPR * 2 + lane * 2 + 1] = f1;
    }
}

extern "C" void kernel_launch(void* const* d_in, const int* in_sizes, int n_in,
                              void* d_out, int out_size, void* d_ws, size_t ws_size,
                              hipStream_t stream) {
    const float* x    = (const float*)d_in[0];
    const int*   row  = (const int*)d_in[1];
    const int*   col  = (const int*)d_in[2];
    const float* vals = (const float*)d_in[3];
    const float* W1 = (const float*)d_in[4];  const float* b1 = (const float*)d_in[5];
    const float* W2 = (const float*)d_in[6];  const float* b2 = (const float*)d_in[7];
    const float* W3 = (const float*)d_in[8];  const float* b3 = (const float*)d_in[9];
    const float* W4 = (const float*)d_in[10]; const float* b4 = (const float*)d_in[11];

    ushort* Xb = (ushort*)d_ws;
    ushort* Hb = Xb;
    ushort* S  = Xb + (size_t)NN * 512;
    ushort* Wt1 = S + (size_t)NN * 256;
    ushort* Wt2 = Wt1 + 512 * 256;
    ushort* Wt3 = Wt2 + 256 * 256;
    ushort* Wt4 = Wt3 + 256 * 128;
    int* cnt    = (int*)(Wt4 + 128 * 128);
    int* rowptr = cnt + NN;
    int* rowcur = rowptr + (NN + 1);
    int* pend   = rowcur + (NN + 1);
    ull* epack  = (ull*)pend;
    int* bsum   = (int*)(epack + NE);
    int* boff   = bsum + SCAN_NB;
    float* out  = (float*)d_out;

    // ---- casts ----
    {
        int n8 = NN * 512 / 8;
        cast_bf16_x8<<<(n8 + 255) / 256, 256, 0, stream>>>((const float4*)x, (u16x8*)Xb, n8);
        cast_transpose_w<<<(512 * 256 + 255) / 256, 256, 0, stream>>>(W1, Wt1, 512, 256);
        cast_transpose_w<<<(256 * 256 + 255) / 256, 256, 0, stream>>>(W2, Wt2, 256, 256);
        cast_transpose_w<<<(256 * 128 + 255) / 256, 256, 0, stream>>>(W3, Wt3, 256, 128);
        cast_transpose_w<<<(128 * 128 + 255) / 256, 256, 0, stream>>>(W4, Wt4, 128, 128);
    }

    // ---- build CSR ----
    hipMemsetAsync(cnt, 0, NN * sizeof(int), stream);
    hist_rows<<<(NE + 255) / 256, 256, 0, stream>>>(row, cnt);
    scan_bsum<<<SCAN_NB, 256, 0, stream>>>(cnt, bsum);
    scan_boff<<<1, 256, 0, stream>>>(bsum, boff, rowptr);
    scan_write<<<SCAN_NB, 256, 0, stream>>>(cnt, boff, rowptr, rowcur);
    scatter_edges<<<(NE + 255) / 256, 256, 0, stream>>>(row, col, vals, rowcur, epack);

    const int MT = (NN + 127) / 128;  // 391

    // layer 1: [50000,512] @ [512,256]
    gemm_bf16<<<dim3(MT, 2), 256, 0, stream>>>(Xb, Wt1, S, NN, 256, 512);
    spmm_gather_bf16<256, true><<<(NN + 7) / 8, 256, 0, stream>>>(S, rowptr, epack, b1, Hb);
    // layer 2
    gemm_bf16<<<dim3(MT, 2), 256, 0, stream>>>(Hb, Wt2, S, NN, 256, 256);
    spmm_gather_bf16<256, true><<<(NN + 7) / 8, 256, 0, stream>>>(S, rowptr, epack, b2, Hb);
    // layer 3
    gemm_bf16<<<dim3(MT, 1), 256, 0, stream>>>(Hb, Wt3, S, NN, 128, 256);
    spmm_gather_bf16<128, true><<<(NN + 15) / 16, 256, 0, stream>>>(S, rowptr, epack, b3, Hb);
    // layer 4
    gemm_bf16<<<dim3(MT, 1), 256, 0, stream>>>(Hb, Wt4, S, NN, 128, 128);
    spmm_gather_bf16<128, false><<<(NN + 15) / 16, 256, 0, stream>>>(S, rowptr, epack, b4, out);
}